// Round 12
// baseline (293.276 us; speedup 1.0000x reference)
//
#include <hip/hip_runtime.h>
#include <hip/hip_fp16.h>

#define N_NODES 100000
#define N_EDGES 1600000
#define D_FEAT  128
#define C_CLS   40
#define ZSTRIDE 32                        // z row = 32 uints = 64 fp16 = 128 B
#define LN_EPS  1e-5f

#define RPB   256                         // rows per bucket
#define NBKT  ((N_NODES + RPB - 1) / RPB) // 391
#define BCAP  6144                        // padded slots/bucket (mean 4096, sigma~64)
#define TILE_E 4096                       // edges per bin block (round-0/6 proven)
#define EBLK  ((N_EDGES + TILE_E - 1) / TILE_E)  // 391
#define NTILES (N_NODES / 16)             // 6250 fc tiles
#define FCB   ((NTILES + 3) / 4)          // 1563 fc blocks (4 waves each)

typedef __attribute__((ext_vector_type(8))) _Float16 half8;
typedef __attribute__((ext_vector_type(4))) float floatx4;
typedef __attribute__((ext_vector_type(2))) float floatx2;
typedef __attribute__((ext_vector_type(2))) int   intx2;
typedef __attribute__((ext_vector_type(4))) unsigned uintx4;

// ---------- fp16 pair pack/unpack (storage only; accumulate fp32) ----------
__device__ inline float2 h2f2(unsigned v) {
    __half2 h = *(__half2*)&v;
    return __half22float2(h);
}
__device__ inline unsigned f2h2(float x, float y) {
    __half2 h = __floats2half2_rn(x, y);
    return *(unsigned*)&h;
}

// ---- prologue: blocks 0..19 convert W fp32->fp16; block 20 zeroes bktsz and
// the pad rows of z0/z1 (merges 3 hipMemsetAsync + wconv into one launch) ----
__global__ __launch_bounds__(256) void init_k(const float* __restrict__ W,
                                              _Float16* __restrict__ wh,
                                              int* __restrict__ bktsz,
                                              unsigned* __restrict__ z0,
                                              unsigned* __restrict__ z1) {
    int t = threadIdx.x;
    if (blockIdx.x < 20) {
        int i = blockIdx.x * 256 + t;
        if (i < C_CLS * D_FEAT) wh[i] = (_Float16)W[i];
        return;
    }
    for (int i = t; i < NBKT; i += 256) bktsz[i] = 0;
    if (t < ZSTRIDE) {
        z0[(size_t)N_NODES * ZSTRIDE + t] = 0u;
        z1[(size_t)N_NODES * ZSTRIDE + t] = 0u;
    }
}

// ---- fused: blocks [0,EBLK) bin edges into buckets; blocks [EBLK,EBLK+FCB)
// compute z0 = feat @ W^T via f16 MFMA (fc-first commute). Round-11 proven.
// csr_tmp[b*BCAP + slot] = (lrow<<17) | col
__global__ __launch_bounds__(256) void fcbin_k(const float* __restrict__ feat,
                                               const _Float16* __restrict__ wh,
                                               const int* __restrict__ row,
                                               const int* __restrict__ col,
                                               int* __restrict__ bktsz,
                                               int* __restrict__ csr_tmp,
                                               unsigned* __restrict__ z) {
    __shared__ int hist[NBKT];
    __shared__ int cbase[NBKT];
    __shared__ _Float16 zl[4][16][72];   // 72-stride pad: breaks quad-bank aliasing
    int t = threadIdx.x;
    if (blockIdx.x < EBLK) {
        // ---------------- edge binning ----------------
        int tile = blockIdx.x * TILE_E;
        for (int i = t; i < NBKT; i += 256) hist[i] = 0;
        __syncthreads();
        int r[16], c[16], pos[16];
        #pragma unroll
        for (int k = 0; k < 16; k++) {
            int e = tile + k * 256 + t;
            if (e < N_EDGES) {
                r[k] = row[e]; c[k] = col[e];
                pos[k] = atomicAdd(&hist[r[k] / RPB], 1);
            } else r[k] = -1;
        }
        __syncthreads();
        for (int i = t; i < NBKT; i += 256) {
            int h = hist[i];
            cbase[i] = h ? atomicAdd(&bktsz[i], h) : 0;
        }
        __syncthreads();
        #pragma unroll
        for (int k = 0; k < 16; k++) {
            if (r[k] >= 0) {
                int b = r[k] / RPB;
                int slot = cbase[b] + pos[k];
                if (slot < BCAP)   // statistically impossible overflow guard
                    csr_tmp[b * BCAP + slot] = ((r[k] & (RPB - 1)) << 17) | c[k];
            }
        }
        return;
    }
    // ---------------- fc: z = feat @ W^T (f16 MFMA, fp32 acc) ----------------
    int wave = t >> 6, lane = t & 63;
    int m = lane & 15, quad = lane >> 4;
    int tile = (blockIdx.x - EBLK) * 4 + wave;
    bool valid = (tile < NTILES);
    int node0 = tile * 16;

    half8 bfrag[3][4];
    if (valid) {
        const half8* wh8 = (const half8*)wh;   // fragment idx = c*16 + ks*4 + quad
        #pragma unroll
        for (int ct = 0; ct < 3; ct++) {
            int c = ct * 16 + m;
            bool ok = (c < C_CLS);
            #pragma unroll
            for (int ks = 0; ks < 4; ks++) {
                if (ok) {
                    bfrag[ct][ks] = wh8[c * 16 + ks * 4 + quad];
                } else {
                    #pragma unroll
                    for (int j = 0; j < 8; j++) bfrag[ct][ks][j] = (_Float16)0.0f;
                }
            }
        }
    }

    floatx4 acc0 = {0.f,0.f,0.f,0.f}, acc1 = acc0, acc2 = acc0;
    if (valid) {
        #pragma unroll
        for (int ks = 0; ks < 4; ks++) {
            const float4* ap = (const float4*)&feat[(node0 + m) * D_FEAT + ks * 32 + quad * 8];
            float4 a0 = ap[0], a1 = ap[1];
            half8 afrag;
            afrag[0] = (_Float16)a0.x; afrag[1] = (_Float16)a0.y;
            afrag[2] = (_Float16)a0.z; afrag[3] = (_Float16)a0.w;
            afrag[4] = (_Float16)a1.x; afrag[5] = (_Float16)a1.y;
            afrag[6] = (_Float16)a1.z; afrag[7] = (_Float16)a1.w;
            acc0 = __builtin_amdgcn_mfma_f32_16x16x32_f16(afrag, bfrag[0][ks], acc0, 0, 0, 0);
            acc1 = __builtin_amdgcn_mfma_f32_16x16x32_f16(afrag, bfrag[1][ks], acc1, 0, 0, 0);
            acc2 = __builtin_amdgcn_mfma_f32_16x16x32_f16(afrag, bfrag[2][ks], acc2, 0, 0, 0);
        }
    }

    // zero pad cols 48..63 (cols 40..47 are exact 0 from zeroed bfrag)
    {
        int zr = lane >> 2;
        uint2 zz = make_uint2(0u, 0u);
        ((uint2*)&zl[wave][zr][48])[lane & 3] = zz;
    }
    // C/D layout: col = ct*16+m, row = quad*4+r
    if (valid) {
        #pragma unroll
        for (int r = 0; r < 4; r++) {
            int zrow = quad * 4 + r;
            zl[wave][zrow][m]      = (_Float16)acc0[r];
            zl[wave][zrow][16 + m] = (_Float16)acc1[r];
            zl[wave][zrow][32 + m] = (_Float16)acc2[r];
        }
    }
    __syncthreads();
    if (valid) {
        int zr = lane >> 2, part = lane & 3;
        uint4 v0 = ((uint4*)&zl[wave][zr][0])[part];
        uint4 v1 = ((uint4*)&zl[wave][zr][0])[part + 4];
        uint4* zg = (uint4*)z;
        zg[(size_t)(node0 + zr) * 8 + part]     = v0;
        zg[(size_t)(node0 + zr) * 8 + part + 4] = v1;
    }
}

// ---- fused refine: hist + scan -> rowinfo/rowc; scatter col-only CSR;
// scale this bucket's z rows by dinv (u = D^{-1/2} z).  Round-10 proven.
__global__ __launch_bounds__(256) void refine_k(const int* __restrict__ csr_tmp,
                                                const int* __restrict__ bktsz,
                                                int2* __restrict__ rowinfo,
                                                float2* __restrict__ rowc,
                                                int* __restrict__ csr_col,
                                                unsigned* __restrict__ z) {
    __shared__ int hist[RPB];
    __shared__ int psc[RPB];
    __shared__ int cur[RPB];
    __shared__ float dl[RPB];
    int b = blockIdx.x, t = threadIdx.x;
    int r0 = b * RPB;
    int nrows = min(RPB, N_NODES - r0);
    hist[t] = 0;
    __syncthreads();
    int cnt = bktsz[b];
    const int* base = csr_tmp + b * BCAP;
    for (int i = t; i < cnt; i += 256)
        atomicAdd(&hist[base[i] >> 17], 1);
    __syncthreads();
    int v = hist[t];
    psc[t] = v;
    __syncthreads();
    for (int off = 1; off < 256; off <<= 1) {
        int x = (t >= off) ? psc[t - off] : 0;
        __syncthreads();
        psc[t] += x;
        __syncthreads();
    }
    int start = b * BCAP + psc[t] - v;     // exclusive prefix, bucket-local
    cur[t] = start;
    float fdeg = (float)v + 1.0f;          // augmented degree
    float inv  = 1.0f / fdeg;
    dl[t] = rsqrtf(fdeg);
    if (t < nrows) {
        rowinfo[r0 + t] = make_int2(start, start + v);
        rowc[r0 + t]    = make_float2(0.5f + 0.5f * inv,  // selfc (u-space)
                                      0.5f * inv);        // row scale for gather sum
    }
    __syncthreads();
    // scatter cols into final CSR (4 B/edge, weight-free)
    for (int i = t; i < cnt; i += 256) {
        int pk = base[i];
        int lr = pk >> 17;
        int p = atomicAdd(&cur[lr], 1);
        csr_col[p] = pk & 0x1FFFF;
    }
    // u = dinv * z for this bucket's rows (coalesced, dinv from LDS)
    int total = nrows * ZSTRIDE;
    unsigned* zb = z + (size_t)r0 * ZSTRIDE;
    for (int i = t; i < total; i += 256) {
        float s = dl[i >> 5];
        float2 f = h2f2(zb[i]);
        zb[i] = f2h2(f.x * s, f.y * s);
    }
}

// ---------------- propagation in u-space: unweighted gather-sum.
// u'[r] = selfc*u[r] + rowscale * sum_edges u[c].  8 lanes/node, 8 nodes/wave.
// csr_col/rowinfo/rowc are read-once streams -> non-temporal loads keep L2
// reserved for the gather-reused z rows (stores stay cacheable: round-5 lesson).
// FINAL fuses h = sqrt(deg)*u, bias, LayerNorm, fp32 out.
template<bool FINAL>
__global__ __launch_bounds__(256) void prop_u_t(const unsigned* __restrict__ hin,
                                                unsigned* __restrict__ hout,
                                                const int2* __restrict__ rowinfo,
                                                const float2* __restrict__ rowc,
                                                const int* __restrict__ csr_col,
                                                const float* __restrict__ bias,
                                                const float* __restrict__ gamma,
                                                const float* __restrict__ beta,
                                                float* __restrict__ out) {
    int t = threadIdx.x;
    int wave = t >> 6, lane = t & 63;
    int q   = lane >> 3;               // which of 8 nodes in the wave
    int sub = lane & 7;                // 8 lanes x uint4 = 128 B per node
    int node = blockIdx.x * 32 + wave * 8 + q;   // N % 32 == 0
    const uintx4* hin4 = (const uintx4*)hin;

    uintx4 hv = hin4[(unsigned)node * 8 + sub];
    floatx2 rc = __builtin_nontemporal_load((const floatx2*)rowc + node);
    float acc[8] = {0.f,0.f,0.f,0.f,0.f,0.f,0.f,0.f};   // gather sum only

    intx2 ri = __builtin_nontemporal_load((const intx2*)rowinfo + node);
    int j = ri.x, end = ri.y;
    int base = ri.x;                   // always a valid csr index for this row region

    int e[8];
    #pragma unroll
    for (int k = 0; k < 8; k++)
        e[k] = __builtin_nontemporal_load(csr_col + ((j + k < end) ? j + k : base));

    while (__any(j < end)) {
        uintx4 g[8];
        #pragma unroll
        for (int k = 0; k < 8; k++) {
            int c = (j + k < end) ? e[k] : N_NODES;   // N_NODES = zeroed pad row
            g[k] = hin4[(unsigned)c * 8 + sub];
        }
        int j2 = j + 8;
        #pragma unroll
        for (int k = 0; k < 8; k++)
            e[k] = __builtin_nontemporal_load(csr_col + ((j2 + k < end) ? j2 + k : base));
        #pragma unroll
        for (int k = 0; k < 8; k++) {
            float2 f0 = h2f2(g[k].x), f1 = h2f2(g[k].y), f2 = h2f2(g[k].z), f3 = h2f2(g[k].w);
            acc[0] += f0.x; acc[1] += f0.y;
            acc[2] += f1.x; acc[3] += f1.y;
            acc[4] += f2.x; acc[5] += f2.y;
            acc[6] += f3.x; acc[7] += f3.y;
        }
        j = j2;
    }

    float2 h0 = h2f2(hv.x), h1 = h2f2(hv.y), h2 = h2f2(hv.z), h3 = h2f2(hv.w);
    float r8[8];
    r8[0] = rc.x * h0.x + rc.y * acc[0]; r8[1] = rc.x * h0.y + rc.y * acc[1];
    r8[2] = rc.x * h1.x + rc.y * acc[2]; r8[3] = rc.x * h1.y + rc.y * acc[3];
    r8[4] = rc.x * h2.x + rc.y * acc[4]; r8[5] = rc.x * h2.y + rc.y * acc[5];
    r8[6] = rc.x * h3.x + rc.y * acc[6]; r8[7] = rc.x * h3.y + rc.y * acc[7];

    if (!FINAL) {
        uintx4 o;
        o.x = f2h2(r8[0], r8[1]);
        o.y = f2h2(r8[2], r8[3]);
        o.z = f2h2(r8[4], r8[5]);
        o.w = f2h2(r8[6], r8[7]);
        ((uintx4*)hout)[(unsigned)node * 8 + sub] = o;
    } else {
        // h = sqrt(deg) * u;  2*selfc - 1 = 1/deg  =>  fscale = rsqrt(1/deg)
        float fs = rsqrtf(2.0f * rc.x - 1.0f);
        bool realsub = (sub < 5);      // cols 0..39 live on sub 0..4
        int cb = sub * 8;
        float vv[8];
        float s = 0.0f, ss = 0.0f;
        #pragma unroll
        for (int i = 0; i < 8; i++) {
            float x = realsub ? (fs * r8[i] + bias[cb + i]) : 0.0f;
            vv[i] = x;
            s += x; ss += x * x;
        }
        s  += __shfl_xor(s, 1);  s  += __shfl_xor(s, 2);  s  += __shfl_xor(s, 4);
        ss += __shfl_xor(ss, 1); ss += __shfl_xor(ss, 2); ss += __shfl_xor(ss, 4);
        float mean = s * (1.0f / C_CLS);
        float var  = ss * (1.0f / C_CLS) - mean * mean;
        float inv  = rsqrtf(var + LN_EPS);
        if (realsub) {
            float o8[8];
            #pragma unroll
            for (int i = 0; i < 8; i++)
                o8[i] = (vv[i] - mean) * inv * gamma[cb + i] + beta[cb + i];
            float* orow = out + (size_t)node * C_CLS + cb;
            ((float4*)orow)[0] = make_float4(o8[0], o8[1], o8[2], o8[3]);
            ((float4*)orow)[1] = make_float4(o8[4], o8[5], o8[6], o8[7]);
        }
    }
}

// ---------------- launch ----------------
extern "C" void kernel_launch(void* const* d_in, const int* in_sizes, int n_in,
                              void* d_out, int out_size, void* d_ws, size_t ws_size,
                              hipStream_t stream) {
    const float* feat  = (const float*)d_in[0];
    const int*   row   = (const int*)d_in[1];
    const int*   col   = (const int*)d_in[2];
    const float* W     = (const float*)d_in[3];
    const float* b     = (const float*)d_in[4];
    const float* gamma = (const float*)d_in[5];
    const float* beta  = (const float*)d_in[6];
    float* out = (float*)d_out;

    char* ws = (char*)d_ws;
    size_t off = 0;
    auto alloc = [&](size_t bytes) {
        size_t o = off;
        off = (off + bytes + 255) & ~(size_t)255;
        return o;
    };
    float2*   rowc     = (float2*)  (ws + alloc((size_t)N_NODES * 8));
    int2*     rowinfo  = (int2*)    (ws + alloc((size_t)N_NODES * 8));
    int*      bktsz    = (int*)     (ws + alloc((size_t)NBKT * 4));
    _Float16* wh       = (_Float16*)(ws + alloc((size_t)C_CLS * D_FEAT * 2));
    int*      csr_tmp  = (int*)     (ws + alloc((size_t)NBKT * BCAP * 4));
    int*      csr_col  = (int*)     (ws + alloc((size_t)NBKT * BCAP * 4));
    unsigned* z0       = (unsigned*)(ws + alloc((size_t)(N_NODES + 8) * ZSTRIDE * 4));
    unsigned* z1       = (unsigned*)(ws + alloc((size_t)(N_NODES + 8) * ZSTRIDE * 4));

    init_k<<<21, 256, 0, stream>>>(W, wh, bktsz, z0, z1);
    fcbin_k<<<EBLK + FCB, 256, 0, stream>>>(feat, wh, row, col, bktsz, csr_tmp, z0);
    refine_k<<<NBKT, 256, 0, stream>>>(csr_tmp, bktsz, rowinfo, rowc, csr_col, z0);

    int pgrid = N_NODES / 32;              // 3125
    prop_u_t<false><<<pgrid, 256, 0, stream>>>(z0, z1, rowinfo, rowc, csr_col,
                                               nullptr, nullptr, nullptr, nullptr);
    prop_u_t<false><<<pgrid, 256, 0, stream>>>(z1, z0, rowinfo, rowc, csr_col,
                                               nullptr, nullptr, nullptr, nullptr);
    prop_u_t<false><<<pgrid, 256, 0, stream>>>(z0, z1, rowinfo, rowc, csr_col,
                                               nullptr, nullptr, nullptr, nullptr);
    prop_u_t<true><<<pgrid, 256, 0, stream>>>(z1, nullptr, rowinfo, rowc, csr_col,
                                              b, gamma, beta, out);
}

// Round 13
// 268.852 us; speedup vs baseline: 1.0908x; 1.0908x over previous
//
#include <hip/hip_runtime.h>
#include <hip/hip_fp16.h>

#define N_NODES 100000
#define N_EDGES 1600000
#define D_FEAT  128
#define C_CLS   40
#define LN_EPS  1e-5f

#define RPB   256                         // rows per bucket
#define NBKT  ((N_NODES + RPB - 1) / RPB) // 391
#define BCAP  6144                        // padded slots/bucket (mean 4096, sigma~64)
#define TILE_E 4096                       // edges per bin block (round-0/6 proven)
#define EBLK  ((N_EDGES + TILE_E - 1) / TILE_E)  // 391
#define NTILES (N_NODES / 16)             // 6250 fc tiles
#define FCB   ((NTILES + 3) / 4)          // 1563 fc blocks (4 waves each)

// ---- sector-split z layout ----
// z_lo: 32 fp16 (64 B) per node, 64-B aligned -> 1 sector per gather.
// z_hi:  8 fp16 (16 B) per node, 1.6 MB total -> L2-resident everywhere.
#define ZPAD  8
#define QLO   ((N_NODES + ZPAD) * 4)      // uint4 index where hi region starts
#define ZBYTES ((size_t)(N_NODES + ZPAD) * 80)

typedef __attribute__((ext_vector_type(8))) _Float16 half8;
typedef __attribute__((ext_vector_type(4))) float floatx4;
typedef __attribute__((ext_vector_type(4))) unsigned uintx4;

// ---------- fp16 pair pack/unpack (storage only; accumulate fp32) ----------
__device__ inline float2 h2f2(unsigned v) {
    __half2 h = *(__half2*)&v;
    return __half22float2(h);
}
__device__ inline unsigned f2h2(float x, float y) {
    __half2 h = __floats2half2_rn(x, y);
    return *(unsigned*)&h;
}

// ---- prologue: blocks 0..19 convert W fp32->fp16; block 20 zeroes bktsz and
// the pad rows (lo+hi) of z0/z1 ----
__global__ __launch_bounds__(256) void init_k(const float* __restrict__ W,
                                              _Float16* __restrict__ wh,
                                              int* __restrict__ bktsz,
                                              unsigned* __restrict__ z0,
                                              unsigned* __restrict__ z1) {
    int t = threadIdx.x;
    if (blockIdx.x < 20) {
        int i = blockIdx.x * 256 + t;
        if (i < C_CLS * D_FEAT) wh[i] = (_Float16)W[i];
        return;
    }
    for (int i = t; i < NBKT; i += 256) bktsz[i] = 0;
    if (t < 16) {   // lo pad row
        z0[(size_t)N_NODES * 16 + t] = 0u;
        z1[(size_t)N_NODES * 16 + t] = 0u;
    }
    if (t < 4) {    // hi pad row
        z0[(size_t)QLO * 4 + (size_t)N_NODES * 4 + t] = 0u;
        z1[(size_t)QLO * 4 + (size_t)N_NODES * 4 + t] = 0u;
    }
}

// ---- fused: blocks [0,EBLK) bin edges into buckets; blocks [EBLK,EBLK+FCB)
// compute z0 = feat @ W^T via f16 MFMA (fc-first commute). Round-11 proven.
// z written in split layout: lo 64 B (cols 0..31) + hi 16 B (cols 32..39).
// csr_tmp[b*BCAP + slot] = (lrow<<17) | col
__global__ __launch_bounds__(256) void fcbin_k(const float* __restrict__ feat,
                                               const _Float16* __restrict__ wh,
                                               const int* __restrict__ row,
                                               const int* __restrict__ col,
                                               int* __restrict__ bktsz,
                                               int* __restrict__ csr_tmp,
                                               unsigned* __restrict__ z) {
    __shared__ int hist[NBKT];
    __shared__ int cbase[NBKT];
    __shared__ _Float16 zl[4][16][72];   // 72-stride pad: breaks quad-bank aliasing
    int t = threadIdx.x;
    if (blockIdx.x < EBLK) {
        // ---------------- edge binning ----------------
        int tile = blockIdx.x * TILE_E;
        for (int i = t; i < NBKT; i += 256) hist[i] = 0;
        __syncthreads();
        int r[16], c[16], pos[16];
        #pragma unroll
        for (int k = 0; k < 16; k++) {
            int e = tile + k * 256 + t;
            if (e < N_EDGES) {
                r[k] = row[e]; c[k] = col[e];
                pos[k] = atomicAdd(&hist[r[k] / RPB], 1);
            } else r[k] = -1;
        }
        __syncthreads();
        for (int i = t; i < NBKT; i += 256) {
            int h = hist[i];
            cbase[i] = h ? atomicAdd(&bktsz[i], h) : 0;
        }
        __syncthreads();
        #pragma unroll
        for (int k = 0; k < 16; k++) {
            if (r[k] >= 0) {
                int b = r[k] / RPB;
                int slot = cbase[b] + pos[k];
                if (slot < BCAP)   // statistically impossible overflow guard
                    csr_tmp[b * BCAP + slot] = ((r[k] & (RPB - 1)) << 17) | c[k];
            }
        }
        return;
    }
    // ---------------- fc: z = feat @ W^T (f16 MFMA, fp32 acc) ----------------
    int wave = t >> 6, lane = t & 63;
    int m = lane & 15, quad = lane >> 4;
    int tile = (blockIdx.x - EBLK) * 4 + wave;
    bool valid = (tile < NTILES);
    int node0 = tile * 16;

    half8 bfrag[3][4];
    if (valid) {
        const half8* wh8 = (const half8*)wh;   // fragment idx = c*16 + ks*4 + quad
        #pragma unroll
        for (int ct = 0; ct < 3; ct++) {
            int c = ct * 16 + m;
            bool ok = (c < C_CLS);
            #pragma unroll
            for (int ks = 0; ks < 4; ks++) {
                if (ok) {
                    bfrag[ct][ks] = wh8[c * 16 + ks * 4 + quad];
                } else {
                    #pragma unroll
                    for (int j = 0; j < 8; j++) bfrag[ct][ks][j] = (_Float16)0.0f;
                }
            }
        }
    }

    floatx4 acc0 = {0.f,0.f,0.f,0.f}, acc1 = acc0, acc2 = acc0;
    if (valid) {
        #pragma unroll
        for (int ks = 0; ks < 4; ks++) {
            const float4* ap = (const float4*)&feat[(node0 + m) * D_FEAT + ks * 32 + quad * 8];
            float4 a0 = ap[0], a1 = ap[1];
            half8 afrag;
            afrag[0] = (_Float16)a0.x; afrag[1] = (_Float16)a0.y;
            afrag[2] = (_Float16)a0.z; afrag[3] = (_Float16)a0.w;
            afrag[4] = (_Float16)a1.x; afrag[5] = (_Float16)a1.y;
            afrag[6] = (_Float16)a1.z; afrag[7] = (_Float16)a1.w;
            acc0 = __builtin_amdgcn_mfma_f32_16x16x32_f16(afrag, bfrag[0][ks], acc0, 0, 0, 0);
            acc1 = __builtin_amdgcn_mfma_f32_16x16x32_f16(afrag, bfrag[1][ks], acc1, 0, 0, 0);
            acc2 = __builtin_amdgcn_mfma_f32_16x16x32_f16(afrag, bfrag[2][ks], acc2, 0, 0, 0);
        }
    }

    // C/D layout: col = ct*16+m, row = quad*4+r  (cols 40..47 are exact zeros)
    if (valid) {
        #pragma unroll
        for (int r = 0; r < 4; r++) {
            int zrow = quad * 4 + r;
            zl[wave][zrow][m]      = (_Float16)acc0[r];
            zl[wave][zrow][16 + m] = (_Float16)acc1[r];
            zl[wave][zrow][32 + m] = (_Float16)acc2[r];
        }
    }
    __syncthreads();
    if (valid) {
        int zr = lane >> 2, part = lane & 3;
        uint4 lo = ((uint4*)&zl[wave][zr][0])[part];          // fp16 part*8 .. +7
        ((uint4*)z)[(size_t)(node0 + zr) * 4 + part] = lo;
        if (part == 0) {
            uint4 hi = *(uint4*)&zl[wave][zr][32];            // fp16 32..39
            ((uint4*)z)[QLO + node0 + zr] = hi;
        }
    }
}

// ---- fused refine: hist + scan -> rowinfo/rowc; scatter col-only CSR;
// scale this bucket's z rows (lo+hi) by dinv (u = D^{-1/2} z). ----
__global__ __launch_bounds__(256) void refine_k(const int* __restrict__ csr_tmp,
                                                const int* __restrict__ bktsz,
                                                int2* __restrict__ rowinfo,
                                                float2* __restrict__ rowc,
                                                int* __restrict__ csr_col,
                                                unsigned* __restrict__ z) {
    __shared__ int hist[RPB];
    __shared__ int psc[RPB];
    __shared__ int cur[RPB];
    __shared__ float dl[RPB];
    int b = blockIdx.x, t = threadIdx.x;
    int r0 = b * RPB;
    int nrows = min(RPB, N_NODES - r0);
    hist[t] = 0;
    __syncthreads();
    int cnt = bktsz[b];
    const int* base = csr_tmp + b * BCAP;
    for (int i = t; i < cnt; i += 256)
        atomicAdd(&hist[base[i] >> 17], 1);
    __syncthreads();
    int v = hist[t];
    psc[t] = v;
    __syncthreads();
    for (int off = 1; off < 256; off <<= 1) {
        int x = (t >= off) ? psc[t - off] : 0;
        __syncthreads();
        psc[t] += x;
        __syncthreads();
    }
    int start = b * BCAP + psc[t] - v;     // exclusive prefix, bucket-local
    cur[t] = start;
    float fdeg = (float)v + 1.0f;          // augmented degree
    float inv  = 1.0f / fdeg;
    dl[t] = rsqrtf(fdeg);
    if (t < nrows) {
        rowinfo[r0 + t] = make_int2(start, start + v);
        rowc[r0 + t]    = make_float2(0.5f + 0.5f * inv,  // selfc (u-space)
                                      0.5f * inv);        // row scale for gather sum
    }
    __syncthreads();
    // scatter cols into final CSR (4 B/edge, weight-free)
    for (int i = t; i < cnt; i += 256) {
        int pk = base[i];
        int lr = pk >> 17;
        int p = atomicAdd(&cur[lr], 1);
        csr_col[p] = pk & 0x1FFFF;
    }
    // u = dinv * z for this bucket's rows (lo region: 16 uints/row)
    int totlo = nrows * 16;
    unsigned* zlo = z + (size_t)r0 * 16;
    for (int i = t; i < totlo; i += 256) {
        float s = dl[i >> 4];
        float2 f = h2f2(zlo[i]);
        zlo[i] = f2h2(f.x * s, f.y * s);
    }
    // hi region: 4 uints/row
    int tothi = nrows * 4;
    unsigned* zhi = z + (size_t)QLO * 4 + (size_t)r0 * 4;
    for (int i = t; i < tothi; i += 256) {
        float s = dl[i >> 2];
        float2 f = h2f2(zhi[i]);
        zhi[i] = f2h2(f.x * s, f.y * s);
    }
}

// ---------------- propagation in u-space, sector-split layout.
// sub 0..3 gather 64-B z_lo rows (1 aligned sector); sub 4 gathers 16-B z_hi
// (1.6 MB, L2-resident); subs 5..7 clamp to sub-4's address (same sector).
// u'[r] = selfc*u[r] + rowscale * sum_edges u[c].
// FINAL fuses h = sqrt(deg)*u, bias, LayerNorm, fp32 out.
template<bool FINAL>
__global__ __launch_bounds__(256) void prop_u_t(const unsigned* __restrict__ hin,
                                                unsigned* __restrict__ hout,
                                                const int2* __restrict__ rowinfo,
                                                const float2* __restrict__ rowc,
                                                const int* __restrict__ csr_col,
                                                const float* __restrict__ bias,
                                                const float* __restrict__ gamma,
                                                const float* __restrict__ beta,
                                                float* __restrict__ out) {
    int t = threadIdx.x;
    int wave = t >> 6, lane = t & 63;
    int q   = lane >> 3;               // which of 8 nodes in the wave
    int sub = lane & 7;
    int node = blockIdx.x * 32 + wave * 8 + q;   // N % 32 == 0
    const uintx4* hin4 = (const uintx4*)hin;

    // per-lane split addressing: idx(c) = c*mul + badd
    int mul  = (sub < 4) ? 4 : 1;
    int badd = (sub < 4) ? sub : QLO;

    uintx4 hv = hin4[(size_t)node * mul + badd];
    float2 rc = rowc[node];            // x = selfc, y = rowscale
    float acc[8] = {0.f,0.f,0.f,0.f,0.f,0.f,0.f,0.f};   // gather sum only

    int2 ri = rowinfo[node];
    int j = ri.x, end = ri.y;
    int base = ri.x;                   // always a valid csr index for this row region

    int e[8];
    #pragma unroll
    for (int k = 0; k < 8; k++)
        e[k] = csr_col[(j + k < end) ? j + k : base];

    while (__any(j < end)) {
        uintx4 g[8];
        #pragma unroll
        for (int k = 0; k < 8; k++) {
            int c = (j + k < end) ? e[k] : N_NODES;   // N_NODES = zeroed pad row
            g[k] = hin4[(size_t)c * mul + badd];
        }
        int j2 = j + 8;
        #pragma unroll
        for (int k = 0; k < 8; k++)
            e[k] = csr_col[(j2 + k < end) ? j2 + k : base];
        #pragma unroll
        for (int k = 0; k < 8; k++) {
            float2 f0 = h2f2(g[k].x), f1 = h2f2(g[k].y), f2 = h2f2(g[k].z), f3 = h2f2(g[k].w);
            acc[0] += f0.x; acc[1] += f0.y;
            acc[2] += f1.x; acc[3] += f1.y;
            acc[4] += f2.x; acc[5] += f2.y;
            acc[6] += f3.x; acc[7] += f3.y;
        }
        j = j2;
    }

    float2 h0 = h2f2(hv.x), h1 = h2f2(hv.y), h2 = h2f2(hv.z), h3 = h2f2(hv.w);
    float r8[8];
    r8[0] = rc.x * h0.x + rc.y * acc[0]; r8[1] = rc.x * h0.y + rc.y * acc[1];
    r8[2] = rc.x * h1.x + rc.y * acc[2]; r8[3] = rc.x * h1.y + rc.y * acc[3];
    r8[4] = rc.x * h2.x + rc.y * acc[4]; r8[5] = rc.x * h2.y + rc.y * acc[5];
    r8[6] = rc.x * h3.x + rc.y * acc[6]; r8[7] = rc.x * h3.y + rc.y * acc[7];

    if (!FINAL) {
        if (sub < 5) {                 // subs 5..7 are duplicates of sub 4
            uintx4 o;
            o.x = f2h2(r8[0], r8[1]);
            o.y = f2h2(r8[2], r8[3]);
            o.z = f2h2(r8[4], r8[5]);
            o.w = f2h2(r8[6], r8[7]);
            ((uintx4*)hout)[(size_t)node * mul + badd] = o;
        }
    } else {
        // h = sqrt(deg) * u;  2*selfc - 1 = 1/deg  =>  fscale = rsqrt(1/deg)
        float fs = rsqrtf(2.0f * rc.x - 1.0f);
        bool realsub = (sub < 5);      // sub s holds cols s*8 .. s*8+7 (s<5)
        int cb = sub * 8;
        float vv[8];
        float s = 0.0f, ss = 0.0f;
        #pragma unroll
        for (int i = 0; i < 8; i++) {
            float x = realsub ? (fs * r8[i] + bias[cb + i]) : 0.0f;
            vv[i] = x;
            s += x; ss += x * x;
        }
        s  += __shfl_xor(s, 1);  s  += __shfl_xor(s, 2);  s  += __shfl_xor(s, 4);
        ss += __shfl_xor(ss, 1); ss += __shfl_xor(ss, 2); ss += __shfl_xor(ss, 4);
        float mean = s * (1.0f / C_CLS);
        float var  = ss * (1.0f / C_CLS) - mean * mean;
        float inv  = rsqrtf(var + LN_EPS);
        if (realsub) {
            float o8[8];
            #pragma unroll
            for (int i = 0; i < 8; i++)
                o8[i] = (vv[i] - mean) * inv * gamma[cb + i] + beta[cb + i];
            float* orow = out + (size_t)node * C_CLS + cb;
            ((float4*)orow)[0] = make_float4(o8[0], o8[1], o8[2], o8[3]);
            ((float4*)orow)[1] = make_float4(o8[4], o8[5], o8[6], o8[7]);
        }
    }
}

// ---------------- launch ----------------
extern "C" void kernel_launch(void* const* d_in, const int* in_sizes, int n_in,
                              void* d_out, int out_size, void* d_ws, size_t ws_size,
                              hipStream_t stream) {
    const float* feat  = (const float*)d_in[0];
    const int*   row   = (const int*)d_in[1];
    const int*   col   = (const int*)d_in[2];
    const float* W     = (const float*)d_in[3];
    const float* b     = (const float*)d_in[4];
    const float* gamma = (const float*)d_in[5];
    const float* beta  = (const float*)d_in[6];
    float* out = (float*)d_out;

    char* ws = (char*)d_ws;
    size_t off = 0;
    auto alloc = [&](size_t bytes) {
        size_t o = off;
        off = (off + bytes + 255) & ~(size_t)255;
        return o;
    };
    float2*   rowc     = (float2*)  (ws + alloc((size_t)N_NODES * 8));
    int2*     rowinfo  = (int2*)    (ws + alloc((size_t)N_NODES * 8));
    int*      bktsz    = (int*)     (ws + alloc((size_t)NBKT * 4));
    _Float16* wh       = (_Float16*)(ws + alloc((size_t)C_CLS * D_FEAT * 2));
    int*      csr_tmp  = (int*)     (ws + alloc((size_t)NBKT * BCAP * 4));
    int*      csr_col  = (int*)     (ws + alloc((size_t)NBKT * BCAP * 4));
    unsigned* z0       = (unsigned*)(ws + alloc(ZBYTES));
    unsigned* z1       = (unsigned*)(ws + alloc(ZBYTES));

    init_k<<<21, 256, 0, stream>>>(W, wh, bktsz, z0, z1);
    fcbin_k<<<EBLK + FCB, 256, 0, stream>>>(feat, wh, row, col, bktsz, csr_tmp, z0);
    refine_k<<<NBKT, 256, 0, stream>>>(csr_tmp, bktsz, rowinfo, rowc, csr_col, z0);

    int pgrid = N_NODES / 32;              // 3125
    prop_u_t<false><<<pgrid, 256, 0, stream>>>(z0, z1, rowinfo, rowc, csr_col,
                                               nullptr, nullptr, nullptr, nullptr);
    prop_u_t<false><<<pgrid, 256, 0, stream>>>(z1, z0, rowinfo, rowc, csr_col,
                                               nullptr, nullptr, nullptr, nullptr);
    prop_u_t<false><<<pgrid, 256, 0, stream>>>(z0, z1, rowinfo, rowc, csr_col,
                                               nullptr, nullptr, nullptr, nullptr);
    prop_u_t<true><<<pgrid, 256, 0, stream>>>(z1, nullptr, rowinfo, rowc, csr_col,
                                              b, gamma, beta, out);
}